// Round 1
// baseline (579.135 us; speedup 1.0000x reference)
//
#include <hip/hip_runtime.h>

#define NEGF (-1e30f)
#define L2E 1.4426950408889634f
#define LN2 0.6931471805599453f

__device__ __forceinline__ float lse2(float a, float b) {
    float m = fmaxf(a, b);
    float s = exp2f((a - m) * L2E) + exp2f((b - m) * L2E);
    return fmaf(log2f(s), LN2, m);
}
__device__ __forceinline__ float lse3(float a, float b, float c) {
    float m = fmaxf(fmaxf(a, b), c);
    float s = exp2f((a - m) * L2E) + exp2f((b - m) * L2E) + exp2f((c - m) * L2E);
    return fmaf(log2f(s), LN2, m);
}

// ---------------- Pass 1: row-wise logsumexp over C=256. One wave per row. ----------------
__global__ __launch_bounds__(256) void lse_kernel(const float* __restrict__ preds,
                                                  float* __restrict__ lse, int rows) {
    int wid = (int)((blockIdx.x * blockDim.x + threadIdx.x) >> 6);
    int lane = threadIdx.x & 63;
    if (wid >= rows) return;
    const float4 v = reinterpret_cast<const float4*>(preds + (size_t)wid * 256)[lane];
    float m = fmaxf(fmaxf(v.x, v.y), fmaxf(v.z, v.w));
#pragma unroll
    for (int off = 32; off; off >>= 1) m = fmaxf(m, __shfl_xor(m, off, 64));
    float s = exp2f((v.x - m) * L2E) + exp2f((v.y - m) * L2E) +
              exp2f((v.z - m) * L2E) + exp2f((v.w - m) * L2E);
#pragma unroll
    for (int off = 32; off; off >>= 1) s += __shfl_xor(s, off, 64);
    if (lane == 0) lse[wid] = fmaf(log2f(s), LN2, m);
}

// ---------------- Pass 2: alpha recursion. One wave per batch element n. ----------------
// Lane l holds extended states 4l..4l+3 in a0..a3, plus a4 = state 4l+4
// (replica of lane l+1's a0; lane 63's a4 is the real state 256).
// Odd state 4l+1 has label targets[2l] (=tA), odd state 4l+3 has targets[2l+1] (=tB).
// Only cross-lane dependency per step: alpha[4l-1] = prev lane's a3 -> one shfl_up.
__global__ __launch_bounds__(64) void ctc_alpha_kernel(const float* __restrict__ preds,
                                                       const int* __restrict__ targets,
                                                       const float* __restrict__ lse,
                                                       float* __restrict__ loss_out) {
    constexpr int T = 1024, C = 256, L = 128, PF = 8;
    const int n = blockIdx.x;
    const int lane = threadIdx.x;
    const float* __restrict__ Pn = preds + (size_t)n * T * C;
    const float* __restrict__ lrow = lse + (size_t)n * T;
    const int* __restrict__ tg = targets + (size_t)n * L;

    const int tA = tg[2 * lane + 0];
    const int tB = tg[2 * lane + 1];
    int tPrev = __shfl_up(tB, 1, 64);
    if (lane == 0) tPrev = 0;  // blank-padded prev2 at s=1
    const bool skipA = (tA != 0) && (tA != tPrev);
    const bool skipB = (tB != 0) && (tB != tA);

    int cnt = (tA != 0) + (tB != 0);
#pragma unroll
    for (int off = 32; off; off >>= 1) cnt += __shfl_xor(cnt, off, 64);
    const int tl = cnt;

    // t = 0 init: state 0 = lp_blank, state 1 = lp[targets[0]], rest = NEG
    const float ls0 = lrow[0];
    float a0 = (lane == 0) ? (Pn[0] - ls0) : NEGF;
    float a1 = (lane == 0) ? (Pn[tA] - ls0) : NEGF;
    float a2 = NEGF, a3 = NEGF, a4 = NEGF;

    // software pipeline, depth PF=8, statically indexed register ring
    float f_b[PF], f_A[PF], f_B[PF], f_l[PF];
#pragma unroll
    for (int j = 0; j < PF; ++j) {
        const float* bp = Pn + (size_t)(1 + j) * C;
        f_b[j] = bp[0]; f_A[j] = bp[tA]; f_B[j] = bp[tB]; f_l[j] = lrow[1 + j];
    }

#define STEP(TT, J) do {                                                        \
        const float inv = f_l[J];                                               \
        const float lpb = f_b[J] - inv;                                         \
        const float lpA = f_A[J] - inv;                                         \
        const float lpB = f_B[J] - inv;                                         \
        const int tn = (TT) + PF;                                               \
        if (tn < T) {                                                           \
            const float* bp = Pn + (size_t)tn * C;                              \
            f_b[J] = bp[0]; f_A[J] = bp[tA]; f_B[J] = bp[tB];                   \
            f_l[J] = lrow[tn];                                                  \
        }                                                                       \
        float p3 = __shfl_up(a3, 1, 64);                                        \
        p3 = (lane == 0) ? NEGF : p3;                                           \
        const float c1 = skipA ? p3 : NEGF;                                     \
        const float c3 = skipB ? a1 : NEGF;                                     \
        const float n0 = lse2(a0, p3) + lpb;                                    \
        const float n1 = lse3(a1, a0, c1) + lpA;                                \
        const float n2 = lse2(a2, a1) + lpb;                                    \
        const float n3 = lse3(a3, a2, c3) + lpB;                                \
        const float n4 = lse2(a4, a3) + lpb;                                    \
        a0 = n0; a1 = n1; a2 = n2; a3 = n3; a4 = n4;                            \
    } while (0)

    // main chunks: t = 1 .. 1016 (127 chunks of 8, slots (t-1)&7 are static)
    for (int tb = 1; tb <= T - 8 - 7; tb += 8) {
        STEP(tb + 0, 0); STEP(tb + 1, 1); STEP(tb + 2, 2); STEP(tb + 3, 3);
        STEP(tb + 4, 4); STEP(tb + 5, 5); STEP(tb + 6, 6); STEP(tb + 7, 7);
    }
    // tail: t = 1017 .. 1023, slots 0..6
    STEP(1017, 0); STEP(1018, 1); STEP(1019, 2); STEP(1020, 3);
    STEP(1021, 4); STEP(1022, 5); STEP(1023, 6);
#undef STEP

    __shared__ float sA[257];
    sA[4 * lane + 0] = a0; sA[4 * lane + 1] = a1;
    sA[4 * lane + 2] = a2; sA[4 * lane + 3] = a3;
    if (lane == 63) sA[256] = a4;
    __syncthreads();
    if (lane == 0) {
        int i1 = 2 * tl;
        int i0 = 2 * tl - 1;
        if (i0 < 0) i0 += 257;   // JAX-style negative index wrap (tl==0 edge)
        if (i1 > 256) i1 = 256;
        const float fin = lse2(sA[i1], sA[i0]);
        const float loss = (fin < -1e29f) ? 0.0f : -fin;
        loss_out[n] = loss / (float)(tl > 0 ? tl : 1);
    }
}

// ---------------- Pass 3: mean over batch ----------------
__global__ __launch_bounds__(64) void reduce_kernel(const float* __restrict__ loss,
                                                    float* __restrict__ out, int N) {
    float s = 0.0f;
    for (int i = threadIdx.x; i < N; i += 64) s += loss[i];
#pragma unroll
    for (int off = 32; off; off >>= 1) s += __shfl_xor(s, off, 64);
    if (threadIdx.x == 0) out[0] = s / (float)N;
}

extern "C" void kernel_launch(void* const* d_in, const int* in_sizes, int n_in,
                              void* d_out, int out_size, void* d_ws, size_t ws_size,
                              hipStream_t stream) {
    const float* preds = (const float*)d_in[0];
    const int* targets = (const int*)d_in[1];
    const int N = in_sizes[1] / 128;          // 128
    const int T = in_sizes[0] / (N * 256);    // 1024
    const int rows = N * T;                   // 131072

    float* lse = (float*)d_ws;                // rows floats (512 KB)
    float* loss = lse + rows;                 // N floats
    float* out = (float*)d_out;

    const int blocks1 = (rows + 3) / 4;       // 4 waves (=4 rows) per 256-thread block
    lse_kernel<<<blocks1, 256, 0, stream>>>(preds, lse, rows);
    ctc_alpha_kernel<<<N, 64, 0, stream>>>(preds, targets, lse, loss);
    reduce_kernel<<<1, 64, 0, stream>>>(loss, out, N);
}

// Round 2
// 515.487 us; speedup vs baseline: 1.1235x; 1.1235x over previous
//
#include <hip/hip_runtime.h>

#define NEGF (-1e30f)
#define L2E 1.4426950408889634f
#define LN2 0.6931471805599453f

__device__ __forceinline__ float lse2(float a, float b) {
    float m = fmaxf(a, b);
    float s = exp2f((a - m) * L2E) + exp2f((b - m) * L2E);
    return fmaf(log2f(s), LN2, m);
}
__device__ __forceinline__ float lse3(float a, float b, float c) {
    float m = fmaxf(fmaxf(a, b), c);
    float s = exp2f((a - m) * L2E) + exp2f((b - m) * L2E) + exp2f((c - m) * L2E);
    return fmaf(log2f(s), LN2, m);
}

// ---------------- Pass 1: fused log-softmax-normalize + label gather ----------------
// Grid: N*64 blocks x 256 threads (4 waves). Wave w handles chunk c = (blk%64)*4 + w,
// i.e. 4 consecutive timesteps. Output layout (t-interleaved for pass-2 coalescing):
//   gath[n][c][j][k] = lp[n][4c+k][ targets[n][j] ]   (j = 0..127, k = 0..3)
//   blank[n][t]      = lp[n][t][0]
__global__ __launch_bounds__(256) void gather_kernel(const float* __restrict__ preds,
                                                     const int* __restrict__ targets,
                                                     float* __restrict__ gath,
                                                     float* __restrict__ blank) {
    constexpr int T = 1024, C = 256, L = 128;
    const int n = blockIdx.x >> 6;
    const int c = ((blockIdx.x & 63) << 2) + (threadIdx.x >> 6);
    const int lane = threadIdx.x & 63;
    const int w = threadIdx.x >> 6;

    const float* __restrict__ P = preds + ((size_t)n * T + (size_t)c * 4) * C;
    const int* __restrict__ tg = targets + (size_t)n * L;
    const int tgA = tg[2 * lane + 0];
    const int tgB = tg[2 * lane + 1];

    __shared__ float sRow[4][4][C];
    float lse_k[4];
#pragma unroll
    for (int k = 0; k < 4; ++k) {
        const float4 v = reinterpret_cast<const float4*>(P + (size_t)k * C)[lane];
        reinterpret_cast<float4*>(&sRow[w][k][0])[lane] = v;
        float m = fmaxf(fmaxf(v.x, v.y), fmaxf(v.z, v.w));
#pragma unroll
        for (int off = 32; off; off >>= 1) m = fmaxf(m, __shfl_xor(m, off, 64));
        float s = exp2f((v.x - m) * L2E) + exp2f((v.y - m) * L2E) +
                  exp2f((v.z - m) * L2E) + exp2f((v.w - m) * L2E);
#pragma unroll
        for (int off = 32; off; off >>= 1) s += __shfl_xor(s, off, 64);
        lse_k[k] = fmaf(log2f(s), LN2, m);
    }
    float4 gA, gB;
    gA.x = sRow[w][0][tgA] - lse_k[0]; gA.y = sRow[w][1][tgA] - lse_k[1];
    gA.z = sRow[w][2][tgA] - lse_k[2]; gA.w = sRow[w][3][tgA] - lse_k[3];
    gB.x = sRow[w][0][tgB] - lse_k[0]; gB.y = sRow[w][1][tgB] - lse_k[1];
    gB.z = sRow[w][2][tgB] - lse_k[2]; gB.w = sRow[w][3][tgB] - lse_k[3];

    float* gp = gath + ((((size_t)n * 256 + c) * 128) + 2 * lane) * 4;
    *reinterpret_cast<float4*>(gp) = gA;
    *reinterpret_cast<float4*>(gp + 4) = gB;
    if (lane == 0) {
        float4 b;
        b.x = sRow[w][0][0] - lse_k[0]; b.y = sRow[w][1][0] - lse_k[1];
        b.z = sRow[w][2][0] - lse_k[2]; b.w = sRow[w][3][0] - lse_k[3];
        *reinterpret_cast<float4*>(blank + (size_t)n * T + (size_t)c * 4) = b;
    }
}

// ---------------- Pass 2: alpha recursion. One wave per batch element n. ----------------
// Lane l holds extended states 4l..4l+3 in a0..a3 plus a4 (replica of lane l+1's a0;
// lane 63's a4 is real state 256). Only cross-lane dep per step: one shfl_up of a3.
// All memory is the compact gathered stream: 32 contiguous B/lane/chunk, prefetched
// 4 chunks (16 steps) ahead in a statically-indexed register ring.
__global__ __launch_bounds__(64, 1) void ctc_alpha_kernel(const float* __restrict__ gath,
                                                          const float* __restrict__ blank,
                                                          const int* __restrict__ targets,
                                                          float* __restrict__ loss_out) {
    constexpr int T = 1024, L = 128;
    const int n = blockIdx.x;
    const int lane = threadIdx.x;
    const int* __restrict__ tg = targets + (size_t)n * L;

    const int tA = tg[2 * lane + 0];
    const int tB = tg[2 * lane + 1];
    int tPrev = __shfl_up(tB, 1, 64);
    if (lane == 0) tPrev = 0;
    const bool skipA = (tA != 0) && (tA != tPrev);
    const bool skipB = (tB != 0) && (tB != tA);

    int cnt = (tA != 0) + (tB != 0);
#pragma unroll
    for (int off = 32; off; off >>= 1) cnt += __shfl_xor(cnt, off, 64);
    const int tl = cnt;

    const float* __restrict__ gn = gath + (size_t)n * (256 * 512);  // 131072 floats
    const float* __restrict__ bn = blank + (size_t)n * T;
    const size_t off = 8 * (size_t)lane;

    // prefetch ring: chunks 0..3
    float4 rA[4], rB[4], rb[4];
#pragma unroll
    for (int s = 0; s < 4; ++s) {
        rA[s] = *reinterpret_cast<const float4*>(gn + (size_t)s * 512 + off);
        rB[s] = *reinterpret_cast<const float4*>(gn + (size_t)s * 512 + off + 4);
        rb[s] = *reinterpret_cast<const float4*>(bn + 4 * s);
    }

    float a0, a1, a2, a3, a4;

#define STEP(LPB, LPA, LPB2) do {                                               \
        float p3 = __shfl_up(a3, 1, 64);                                        \
        p3 = (lane == 0) ? NEGF : p3;                                           \
        const float c1 = skipA ? p3 : NEGF;                                     \
        const float c3 = skipB ? a1 : NEGF;                                     \
        const float n0 = lse2(a0, p3) + (LPB);                                  \
        const float n1 = lse3(a1, a0, c1) + (LPA);                              \
        const float n2 = lse2(a2, a1) + (LPB);                                  \
        const float n3 = lse3(a3, a2, c3) + (LPB2);                             \
        const float n4 = lse2(a4, a3) + (LPB);                                  \
        a0 = n0; a1 = n1; a2 = n2; a3 = n3; a4 = n4;                            \
    } while (0)

#define CHUNK(S, CNEXT) do {                                                    \
        const float4 A = rA[S], B = rB[S], bb = rb[S];                          \
        rA[S] = *reinterpret_cast<const float4*>(gn + (size_t)(CNEXT) * 512 + off);      \
        rB[S] = *reinterpret_cast<const float4*>(gn + (size_t)(CNEXT) * 512 + off + 4);  \
        rb[S] = *reinterpret_cast<const float4*>(bn + 4 * (CNEXT));             \
        STEP(bb.x, A.x, B.x); STEP(bb.y, A.y, B.y);                             \
        STEP(bb.z, A.z, B.z); STEP(bb.w, A.w, B.w);                             \
    } while (0)

    // chunk 0: t=0 init + steps t=1..3
    {
        const float4 A = rA[0], B = rB[0], bb = rb[0];
        rA[0] = *reinterpret_cast<const float4*>(gn + (size_t)4 * 512 + off);
        rB[0] = *reinterpret_cast<const float4*>(gn + (size_t)4 * 512 + off + 4);
        rb[0] = *reinterpret_cast<const float4*>(bn + 16);
        a0 = (lane == 0) ? bb.x : NEGF;
        a1 = (lane == 0) ? A.x : NEGF;
        a2 = NEGF; a3 = NEGF; a4 = NEGF;
        STEP(bb.y, A.y, B.y); STEP(bb.z, A.z, B.z); STEP(bb.w, A.w, B.w);
    }
    CHUNK(1, 5); CHUNK(2, 6); CHUNK(3, 7);
    for (int cb = 4; cb < 256; cb += 4) {
        // OOB prefetches (chunks 256..259) land in the blank/loss ws arrays — allocated, unused.
        CHUNK(0, cb + 4); CHUNK(1, cb + 5); CHUNK(2, cb + 6); CHUNK(3, cb + 7);
    }
#undef CHUNK
#undef STEP

    __shared__ float sA[257];
    sA[4 * lane + 0] = a0; sA[4 * lane + 1] = a1;
    sA[4 * lane + 2] = a2; sA[4 * lane + 3] = a3;
    if (lane == 63) sA[256] = a4;
    __syncthreads();
    if (lane == 0) {
        int i1 = 2 * tl;
        int i0 = 2 * tl - 1;
        if (i0 < 0) i0 += 257;
        if (i1 > 256) i1 = 256;
        const float fin = lse2(sA[i1], sA[i0]);
        const float loss = (fin < -1e29f) ? 0.0f : -fin;
        loss_out[n] = loss / (float)(tl > 0 ? tl : 1);
    }
}

// ---------------- Pass 3: mean over batch ----------------
__global__ __launch_bounds__(64) void reduce_kernel(const float* __restrict__ loss,
                                                    float* __restrict__ out, int N) {
    float s = 0.0f;
    for (int i = threadIdx.x; i < N; i += 64) s += loss[i];
#pragma unroll
    for (int off = 32; off; off >>= 1) s += __shfl_xor(s, off, 64);
    if (threadIdx.x == 0) out[0] = s / (float)N;
}

extern "C" void kernel_launch(void* const* d_in, const int* in_sizes, int n_in,
                              void* d_out, int out_size, void* d_ws, size_t ws_size,
                              hipStream_t stream) {
    const float* preds = (const float*)d_in[0];
    const int* targets = (const int*)d_in[1];
    const int N = in_sizes[1] / 128;          // 128
    const int T = 1024;

    // ws layout: gath [N*131072] | blank [N*T] | loss [N]   (~64.6 MB)
    float* gath = (float*)d_ws;
    float* blank = gath + (size_t)N * 131072;
    float* loss = blank + (size_t)N * T;
    float* out = (float*)d_out;

    gather_kernel<<<N * 64, 256, 0, stream>>>(preds, targets, gath, blank);
    ctc_alpha_kernel<<<N, 64, 0, stream>>>(gath, blank, targets, loss);
    reduce_kernel<<<1, 64, 0, stream>>>(loss, out, N);
}

// Round 4
// 296.148 us; speedup vs baseline: 1.9556x; 1.7406x over previous
//
#include <hip/hip_runtime.h>

#define L2E 1.4426950408889634f
#define LN2D 0.6931471805599453

// ---- async global->LDS DMA (16B per lane: lds_base + lane*16) ----
__device__ __forceinline__ void async_copy16(const float* g, float* l) {
    __builtin_amdgcn_global_load_lds(
        (const __attribute__((address_space(1))) void*)g,
        (__attribute__((address_space(3))) void*)l, 16, 0, 0);
}
// s_waitcnt vmcnt(14), lgkmcnt/expcnt untouched: imm = 0xE | (7<<4) | (0xF<<8) = 0xF7E
__device__ __forceinline__ void wait_vm14() { __builtin_amdgcn_s_waitcnt(0x0F7E); }

// wave-wide max of int, broadcast via readlane(63). Off critical path; any
// wave-uniform result is correctness-safe (only positions the f64 window).
__device__ __forceinline__ int wave_imax(int v) {
    int t;
#define DM(ctrl) t = __builtin_amdgcn_update_dpp(v, v, (ctrl), 0xF, 0xF, false); v = (v > t) ? v : t
    DM(0x111); DM(0x112); DM(0x114); DM(0x118);  // row_shr 1,2,4,8
    DM(0x142); DM(0x143);                        // row_bcast 15, 31
#undef DM
    return __builtin_amdgcn_readlane(v, 63);
}

// ---------------- Pass 1: fused softmax + label gather (probabilities) ----------------
// gath[n][c][j][k] = softmax(preds[n][4c+k])[targets[n][j]], blank[n][t] = softmax[...][0]
__global__ __launch_bounds__(256) void gather_kernel(const float* __restrict__ preds,
                                                     const int* __restrict__ targets,
                                                     float* __restrict__ gath,
                                                     float* __restrict__ blank) {
    constexpr int T = 1024, C = 256, L = 128;
    const int n = blockIdx.x >> 6;
    const int c = ((blockIdx.x & 63) << 2) + (threadIdx.x >> 6);
    const int lane = threadIdx.x & 63;
    const int w = threadIdx.x >> 6;

    const float* __restrict__ P = preds + ((size_t)n * T + (size_t)c * 4) * C;
    const int* __restrict__ tg = targets + (size_t)n * L;
    const int tgA = tg[2 * lane + 0];
    const int tgB = tg[2 * lane + 1];

    __shared__ float sRow[4][4][C];
    float m_k[4], r_k[4];
#pragma unroll
    for (int k = 0; k < 4; ++k) {
        const float4 v = reinterpret_cast<const float4*>(P + (size_t)k * C)[lane];
        reinterpret_cast<float4*>(&sRow[w][k][0])[lane] = v;
        float m = fmaxf(fmaxf(v.x, v.y), fmaxf(v.z, v.w));
#pragma unroll
        for (int off = 32; off; off >>= 1) m = fmaxf(m, __shfl_xor(m, off, 64));
        float s = exp2f((v.x - m) * L2E) + exp2f((v.y - m) * L2E) +
                  exp2f((v.z - m) * L2E) + exp2f((v.w - m) * L2E);
#pragma unroll
        for (int off = 32; off; off >>= 1) s += __shfl_xor(s, off, 64);
        m_k[k] = m; r_k[k] = 1.0f / s;
    }
    float4 gA, gB;
    gA.x = exp2f((sRow[w][0][tgA] - m_k[0]) * L2E) * r_k[0];
    gA.y = exp2f((sRow[w][1][tgA] - m_k[1]) * L2E) * r_k[1];
    gA.z = exp2f((sRow[w][2][tgA] - m_k[2]) * L2E) * r_k[2];
    gA.w = exp2f((sRow[w][3][tgA] - m_k[3]) * L2E) * r_k[3];
    gB.x = exp2f((sRow[w][0][tgB] - m_k[0]) * L2E) * r_k[0];
    gB.y = exp2f((sRow[w][1][tgB] - m_k[1]) * L2E) * r_k[1];
    gB.z = exp2f((sRow[w][2][tgB] - m_k[2]) * L2E) * r_k[2];
    gB.w = exp2f((sRow[w][3][tgB] - m_k[3]) * L2E) * r_k[3];

    float* gp = gath + ((((size_t)n * 256 + c) * 128) + 2 * lane) * 4;
    *reinterpret_cast<float4*>(gp) = gA;
    *reinterpret_cast<float4*>(gp + 4) = gB;
    if (lane == 0) {
        float4 b;
        b.x = exp2f((sRow[w][0][0] - m_k[0]) * L2E) * r_k[0];
        b.y = exp2f((sRow[w][1][0] - m_k[1]) * L2E) * r_k[1];
        b.z = exp2f((sRow[w][2][0] - m_k[2]) * L2E) * r_k[2];
        b.w = exp2f((sRow[w][3][0] - m_k[3]) * L2E) * r_k[3];
        *reinterpret_cast<float4*>(blank + (size_t)n * T + (size_t)c * 4) = b;
    }
}

// ---------------- Pass 2: alpha recursion, f64 linear space. One wave per n. ----------------
// Lane l holds states 4l..4l+3 (A0..A3) + A4 = replica of lane l+1's A0 (lane63: state 256).
// Cross-lane dep per step: alpha[4l-1] = prev lane's A3 via shfl_up (proven R1/R2).
// Stream staged via LDS ring (16 slots x 2KB) filled by global_load_lds, prefetch dist 8
// chunks; explicit vmcnt(14) per chunk. Power-of-2 rescale every 8 steps, exponent in K.
__global__ __launch_bounds__(64) void ctc_alpha_kernel(const float* __restrict__ gath,
                                                       const float* __restrict__ blank,
                                                       const int* __restrict__ targets,
                                                       float* __restrict__ loss_out) {
    constexpr int T = 1024, L = 128, DIST = 8;
    __shared__ float sG[16 * 512];     // 32 KB ring
    __shared__ float sBlank[T];        // 4 KB
    __shared__ double sFin[257];

    const int n = blockIdx.x;
    const int lane = threadIdx.x;
    const int* __restrict__ tg = targets + (size_t)n * L;

    const int tA = tg[2 * lane + 0];
    const int tB = tg[2 * lane + 1];
    int tPrev = __shfl_up(tB, 1, 64);
    if (lane == 0) tPrev = 0;
    const bool skipA = (tA != 0) && (tA != tPrev);
    const bool skipB = (tB != 0) && (tB != tA);

    int cnt = (tA != 0) + (tB != 0);
#pragma unroll
    for (int off = 32; off; off >>= 1) cnt += __shfl_xor(cnt, off, 64);
    const int tl = cnt;

    const float* __restrict__ gn = gath + (size_t)n * 131072;
    const float* __restrict__ bn = blank + (size_t)n * T;

    // preload all blank probs (4 KB) + first DIST chunks into the ring
#pragma unroll
    for (int i = 0; i < 4; ++i) async_copy16(bn + i * 256 + lane * 4, &sBlank[i * 256]);
#pragma unroll
    for (int c = 0; c < DIST; ++c) {
        async_copy16(gn + c * 512 + lane * 4, &sG[c * 512]);
        async_copy16(gn + c * 512 + 256 + lane * 4, &sG[c * 512 + 256]);
    }

    double A0, A1, A2, A3, A4;
    double sc = 1.0;
    int e_apply = 0, K = 0;

    // Wait for this chunk's DMA, read fragments from LDS, kick prefetch for c+DIST.
    // (Prefetch writes slot (c+8)&15 != (c)&15; its previous contents were consumed
    //  8 chunks ago. OOB chunks 256..263 read the blank ws region — allocated.)
#define LOADCHUNK(CC, AF, BF, BB) do {                                          \
        wait_vm14();                                                            \
        const int slot_ = (CC) & 15;                                            \
        AF = *reinterpret_cast<const float4*>(&sG[slot_ * 512 + 8 * lane]);     \
        BF = *reinterpret_cast<const float4*>(&sG[slot_ * 512 + 8 * lane + 4]); \
        BB = *reinterpret_cast<const float4*>(&sBlank[4 * (CC)]);               \
        const int cp_ = (CC) + DIST, sp_ = cp_ & 15;                            \
        async_copy16(gn + cp_ * 512 + lane * 4, &sG[sp_ * 512]);                \
        async_copy16(gn + cp_ * 512 + 256 + lane * 4, &sG[sp_ * 512 + 256]);    \
    } while (0)

#define STEP(PB, PA, PB2) do {                                                  \
        double p3 = __shfl_up(A3, 1, 64);                                       \
        p3 = lane ? p3 : 0.0;                                                   \
        const double u0 = A0 + p3;                                              \
        const double u1 = A1 + A0 + (skipA ? p3 : 0.0);                         \
        const double u2 = A2 + A1;                                              \
        const double u3 = A3 + A2 + (skipB ? A1 : 0.0);                         \
        const double u4 = A4 + A3;                                              \
        A0 = u0 * (PB); A1 = u1 * (PA); A2 = u2 * (PB);                         \
        A3 = u3 * (PB2); A4 = u4 * (PB);                                        \
    } while (0)

#define DOCHUNK(CC) do {                                                        \
        float4 Af_, Bf_, bb_;                                                   \
        LOADCHUNK(CC, Af_, Bf_, bb_);                                           \
        STEP((double)bb_.x, (double)Af_.x, (double)Bf_.x);                      \
        STEP((double)bb_.y, (double)Af_.y, (double)Bf_.y);                      \
        STEP((double)bb_.z, (double)Af_.z, (double)Bf_.z);                      \
        STEP((double)bb_.w, (double)Af_.w, (double)Bf_.w);                      \
    } while (0)

    // Apply scale measured last boundary (exact power of 2), then measure anew —
    // measurement latency hides over the next 8 steps.
#define RESCALE() do {                                                          \
        A0 *= sc; A1 *= sc; A2 *= sc; A3 *= sc; A4 *= sc; K += e_apply;         \
        const double m_ = fmax(fmax(fmax(A0, A1), fmax(A2, A3)), A4);           \
        int e_ = ((__double2hiint(m_) >> 20) & 0x7FF) - 1023;                   \
        e_ = wave_imax(e_);                                                     \
        e_ = e_ < -960 ? -960 : (e_ > 960 ? 960 : e_);                          \
        e_apply = e_;                                                           \
        sc = __hiloint2double((1023 - e_) << 20, 0);                            \
    } while (0)

    // chunk 0: t=0 init + steps t=1..3
    {
        float4 Af_, Bf_, bb_;
        LOADCHUNK(0, Af_, Bf_, bb_);
        A0 = lane ? 0.0 : (double)bb_.x;
        A1 = lane ? 0.0 : (double)Af_.x;
        A2 = 0.0; A3 = 0.0; A4 = 0.0;
        STEP((double)bb_.y, (double)Af_.y, (double)Bf_.y);
        STEP((double)bb_.z, (double)Af_.z, (double)Bf_.z);
        STEP((double)bb_.w, (double)Af_.w, (double)Bf_.w);
    }
    for (int c = 1; c < 255; c += 2) {
        DOCHUNK(c);
        RESCALE();
        DOCHUNK(c + 1);
    }
    DOCHUNK(255);
    RESCALE();
#undef RESCALE
#undef DOCHUNK
#undef STEP
#undef LOADCHUNK

    sFin[4 * lane + 0] = A0; sFin[4 * lane + 1] = A1;
    sFin[4 * lane + 2] = A2; sFin[4 * lane + 3] = A3;
    if (lane == 63) sFin[256] = A4;
    __syncthreads();
    if (lane == 0) {
        int i1 = 2 * tl;
        int i0 = 2 * tl - 1;
        if (i0 < 0) i0 += 257;
        if (i1 > 256) i1 = 256;
        const double fin = sFin[i1] + sFin[i0];
        // true log-prob = (log2(fin) + K) * ln2; vanished -> zero_infinity
        const double loss = (fin > 0.0) ? -(log2(fin) + (double)K) * LN2D : 0.0;
        loss_out[n] = (float)(loss / (double)(tl > 0 ? tl : 1));
    }
}

// ---------------- Pass 3: mean over batch ----------------
__global__ __launch_bounds__(64) void reduce_kernel(const float* __restrict__ loss,
                                                    float* __restrict__ out, int N) {
    float s = 0.0f;
    for (int i = threadIdx.x; i < N; i += 64) s += loss[i];
#pragma unroll
    for (int off = 32; off; off >>= 1) s += __shfl_xor(s, off, 64);
    if (threadIdx.x == 0) out[0] = s / (float)N;
}

extern "C" void kernel_launch(void* const* d_in, const int* in_sizes, int n_in,
                              void* d_out, int out_size, void* d_ws, size_t ws_size,
                              hipStream_t stream) {
    const float* preds = (const float*)d_in[0];
    const int* targets = (const int*)d_in[1];
    const int N = in_sizes[1] / 128;          // 128
    const int T = 1024;

    // ws layout: gath [N*131072] | blank [N*T] | loss [N]   (~64.6 MB)
    float* gath = (float*)d_ws;
    float* blank = gath + (size_t)N * 131072;
    float* loss = blank + (size_t)N * T;
    float* out = (float*)d_out;

    gather_kernel<<<N * 64, 256, 0, stream>>>(preds, targets, gath, blank);
    ctc_alpha_kernel<<<N, 64, 0, stream>>>(gath, blank, targets, loss);
    reduce_kernel<<<1, 64, 0, stream>>>(loss, out, N);
}

// Round 5
// 282.190 us; speedup vs baseline: 2.0523x; 1.0495x over previous
//
#include <hip/hip_runtime.h>

#define L2E 1.4426950408889634f
#define LN2D 0.6931471805599453

// ---- async global->LDS DMA (16B per lane: lds_base + lane*16) ----
__device__ __forceinline__ void async_copy16(const float* g, float* l) {
    __builtin_amdgcn_global_load_lds(
        (const __attribute__((address_space(1))) void*)g,
        (__attribute__((address_space(3))) void*)l, 16, 0, 0);
}
// s_waitcnt vmcnt(14): imm = 0xE | (7<<4) | (0xF<<8) = 0xF7E (gfx9 encoding)
__device__ __forceinline__ void wait_vm14() { __builtin_amdgcn_s_waitcnt(0x0F7E); }

// double lane-shift-right-by-1 via DPP wf_sr1: pure VALU, lane 0 -> +0.0 (bound_ctrl).
__device__ __forceinline__ double dpp_sr1_f64(double x) {
    const int lo = __builtin_amdgcn_update_dpp(0, __double2loint(x), 0x138, 0xF, 0xF, true);
    const int hi = __builtin_amdgcn_update_dpp(0, __double2hiint(x), 0x138, 0xF, 0xF, true);
    return __hiloint2double(hi, lo);
}

// wave-wide max of int, broadcast via readlane(63). Off critical path; only
// positions the f64 scaling window (any wave-uniform value is correctness-safe).
__device__ __forceinline__ int wave_imax(int v) {
    int t;
#define DM(ctrl) t = __builtin_amdgcn_update_dpp(v, v, (ctrl), 0xF, 0xF, false); v = (v > t) ? v : t
    DM(0x111); DM(0x112); DM(0x114); DM(0x118);  // row_shr 1,2,4,8
    DM(0x142); DM(0x143);                        // row_bcast 15, 31
#undef DM
    return __builtin_amdgcn_readlane(v, 63);
}

// ---------------- Pass 1: fused softmax + label gather (probabilities) ----------------
// Chunk c = 4 timesteps. Output chunk layout (conflict-free for pass-2 LDS reads):
//   gath[n][c][    lane*4 + k] = softmax(preds[n][4c+k])[targets[n][2*lane]]     (A block)
//   gath[n][c][256+lane*4 + k] = softmax(preds[n][4c+k])[targets[n][2*lane+1]]   (B block)
//   blank[n][t] = softmax(preds[n][t])[0]
__global__ __launch_bounds__(256) void gather_kernel(const float* __restrict__ preds,
                                                     const int* __restrict__ targets,
                                                     float* __restrict__ gath,
                                                     float* __restrict__ blank) {
    constexpr int T = 1024, C = 256, L = 128;
    const int n = blockIdx.x >> 6;
    const int c = ((blockIdx.x & 63) << 2) + (threadIdx.x >> 6);
    const int lane = threadIdx.x & 63;
    const int w = threadIdx.x >> 6;

    const float* __restrict__ P = preds + ((size_t)n * T + (size_t)c * 4) * C;
    const int* __restrict__ tg = targets + (size_t)n * L;
    const int tgA = tg[2 * lane + 0];
    const int tgB = tg[2 * lane + 1];

    __shared__ float sRow[4][4][C];
    float m_k[4], r_k[4];
#pragma unroll
    for (int k = 0; k < 4; ++k) {
        const float4 v = reinterpret_cast<const float4*>(P + (size_t)k * C)[lane];
        reinterpret_cast<float4*>(&sRow[w][k][0])[lane] = v;
        float m = fmaxf(fmaxf(v.x, v.y), fmaxf(v.z, v.w));
#pragma unroll
        for (int off = 32; off; off >>= 1) m = fmaxf(m, __shfl_xor(m, off, 64));
        float s = exp2f((v.x - m) * L2E) + exp2f((v.y - m) * L2E) +
                  exp2f((v.z - m) * L2E) + exp2f((v.w - m) * L2E);
#pragma unroll
        for (int off = 32; off; off >>= 1) s += __shfl_xor(s, off, 64);
        m_k[k] = m; r_k[k] = 1.0f / s;
    }
    float4 gA, gB;
    gA.x = exp2f((sRow[w][0][tgA] - m_k[0]) * L2E) * r_k[0];
    gA.y = exp2f((sRow[w][1][tgA] - m_k[1]) * L2E) * r_k[1];
    gA.z = exp2f((sRow[w][2][tgA] - m_k[2]) * L2E) * r_k[2];
    gA.w = exp2f((sRow[w][3][tgA] - m_k[3]) * L2E) * r_k[3];
    gB.x = exp2f((sRow[w][0][tgB] - m_k[0]) * L2E) * r_k[0];
    gB.y = exp2f((sRow[w][1][tgB] - m_k[1]) * L2E) * r_k[1];
    gB.z = exp2f((sRow[w][2][tgB] - m_k[2]) * L2E) * r_k[2];
    gB.w = exp2f((sRow[w][3][tgB] - m_k[3]) * L2E) * r_k[3];

    float* gp = gath + ((size_t)n * 256 + c) * 512;
    *reinterpret_cast<float4*>(gp + 4 * lane) = gA;
    *reinterpret_cast<float4*>(gp + 256 + 4 * lane) = gB;
    if (lane == 0) {
        float4 b;
        b.x = exp2f((sRow[w][0][0] - m_k[0]) * L2E) * r_k[0];
        b.y = exp2f((sRow[w][1][0] - m_k[1]) * L2E) * r_k[1];
        b.z = exp2f((sRow[w][2][0] - m_k[2]) * L2E) * r_k[2];
        b.w = exp2f((sRow[w][3][0] - m_k[3]) * L2E) * r_k[3];
        *reinterpret_cast<float4*>(blank + (size_t)n * T + (size_t)c * 4) = b;
    }
}

// ---------------- Pass 2: alpha recursion, f64 linear space. One wave per n. ----------------
// Lane l holds states 4l..4l+3 (A0..A3) + A4 = replica of lane l+1's A0 (lane63: state 256).
// Cross-lane dep per step: alpha[4l-1] = prev lane's A3 via DPP wf_sr1 (VALU, no DS pipe).
// Stream staged via LDS ring (16 slots x 2KB) filled by global_load_lds, prefetch dist 8
// chunks; explicit vmcnt(14) per chunk. Power-of-2 rescale every 8 steps, exponent in K.
__global__ __launch_bounds__(64) void ctc_alpha_kernel(const float* __restrict__ gath,
                                                       const float* __restrict__ blank,
                                                       const int* __restrict__ targets,
                                                       float* __restrict__ loss_out) {
    constexpr int T = 1024, L = 128, DIST = 8;
    __shared__ float sG[16 * 512];     // 32 KB ring
    __shared__ float sBlank[T];        // 4 KB
    __shared__ double sFin[257];

    const int n = blockIdx.x;
    const int lane = threadIdx.x;
    const int* __restrict__ tg = targets + (size_t)n * L;

    const int tA = tg[2 * lane + 0];
    const int tB = tg[2 * lane + 1];
    int tPrev = __shfl_up(tB, 1, 64);
    if (lane == 0) tPrev = 0;
    const bool skipA = (tA != 0) && (tA != tPrev);
    const bool skipB = (tB != 0) && (tB != tA);

    int cnt = (tA != 0) + (tB != 0);
#pragma unroll
    for (int off = 32; off; off >>= 1) cnt += __shfl_xor(cnt, off, 64);
    const int tl = cnt;

    const float* __restrict__ gn = gath + (size_t)n * 131072;
    const float* __restrict__ bn = blank + (size_t)n * T;

    // preload all blank probs (4 KB) + first DIST chunks into the ring
#pragma unroll
    for (int i = 0; i < 4; ++i) async_copy16(bn + i * 256 + lane * 4, &sBlank[i * 256]);
#pragma unroll
    for (int c = 0; c < DIST; ++c) {
        async_copy16(gn + c * 512 + lane * 4, &sG[c * 512]);
        async_copy16(gn + c * 512 + 256 + lane * 4, &sG[c * 512 + 256]);
    }

    double A0, A1, A2, A3, A4;
    double sc = 1.0;
    int e_apply = 0, K = 0;

    // Wait for this chunk's DMA, read fragments (16B/lane stride: conflict-free),
    // kick prefetch for c+DIST. OOB chunks 256..263 read the blank ws region.
#define LOADCHUNK(CC, AF, BF, BB) do {                                          \
        wait_vm14();                                                            \
        const int slot_ = (CC) & 15;                                            \
        AF = *reinterpret_cast<const float4*>(&sG[slot_ * 512 + 4 * lane]);     \
        BF = *reinterpret_cast<const float4*>(&sG[slot_ * 512 + 256 + 4 * lane]); \
        BB = *reinterpret_cast<const float4*>(&sBlank[4 * (CC)]);               \
        const int cp_ = (CC) + DIST, sp_ = cp_ & 15;                            \
        async_copy16(gn + cp_ * 512 + lane * 4, &sG[sp_ * 512]);                \
        async_copy16(gn + cp_ * 512 + 256 + lane * 4, &sG[sp_ * 512 + 256]);    \
    } while (0)

#define STEP(PB, PA, PB2) do {                                                  \
        const double p3 = dpp_sr1_f64(A3);                                      \
        const double u0 = A0 + p3;                                              \
        const double u1 = A1 + A0 + (skipA ? p3 : 0.0);                         \
        const double u2 = A2 + A1;                                              \
        const double u3 = A3 + A2 + (skipB ? A1 : 0.0);                         \
        const double u4 = A4 + A3;                                              \
        A0 = u0 * (PB); A1 = u1 * (PA); A2 = u2 * (PB);                         \
        A3 = u3 * (PB2); A4 = u4 * (PB);                                        \
    } while (0)

#define DOCHUNK(CC) do {                                                        \
        float4 Af_, Bf_, bb_;                                                   \
        LOADCHUNK(CC, Af_, Bf_, bb_);                                           \
        STEP((double)bb_.x, (double)Af_.x, (double)Bf_.x);                      \
        STEP((double)bb_.y, (double)Af_.y, (double)Bf_.y);                      \
        STEP((double)bb_.z, (double)Af_.z, (double)Bf_.z);                      \
        STEP((double)bb_.w, (double)Af_.w, (double)Bf_.w);                      \
    } while (0)

    // Apply scale measured last boundary (exact power of 2), then measure anew —
    // measurement latency hides over the next 8 steps.
#define RESCALE() do {                                                          \
        A0 *= sc; A1 *= sc; A2 *= sc; A3 *= sc; A4 *= sc; K += e_apply;         \
        const double m_ = fmax(fmax(fmax(A0, A1), fmax(A2, A3)), A4);           \
        int e_ = ((__double2hiint(m_) >> 20) & 0x7FF) - 1023;                   \
        e_ = wave_imax(e_);                                                     \
        e_ = e_ < -960 ? -960 : (e_ > 960 ? 960 : e_);                          \
        e_apply = e_;                                                           \
        sc = __hiloint2double((1023 - e_) << 20, 0);                            \
    } while (0)

    // chunk 0: t=0 init + steps t=1..3
    {
        float4 Af_, Bf_, bb_;
        LOADCHUNK(0, Af_, Bf_, bb_);
        A0 = lane ? 0.0 : (double)bb_.x;
        A1 = lane ? 0.0 : (double)Af_.x;
        A2 = 0.0; A3 = 0.0; A4 = 0.0;
        STEP((double)bb_.y, (double)Af_.y, (double)Bf_.y);
        STEP((double)bb_.z, (double)Af_.z, (double)Bf_.z);
        STEP((double)bb_.w, (double)Af_.w, (double)Bf_.w);
    }
    for (int c = 1; c < 255; c += 2) {
        DOCHUNK(c);
        RESCALE();
        DOCHUNK(c + 1);
    }
    DOCHUNK(255);
    RESCALE();
#undef RESCALE
#undef DOCHUNK
#undef STEP
#undef LOADCHUNK

    sFin[4 * lane + 0] = A0; sFin[4 * lane + 1] = A1;
    sFin[4 * lane + 2] = A2; sFin[4 * lane + 3] = A3;
    if (lane == 63) sFin[256] = A4;
    __syncthreads();
    if (lane == 0) {
        int i1 = 2 * tl;
        int i0 = 2 * tl - 1;
        if (i0 < 0) i0 += 257;
        if (i1 > 256) i1 = 256;
        const double fin = sFin[i1] + sFin[i0];
        // true log-prob = (log2(fin) + K) * ln2; vanished -> zero_infinity
        const double loss = (fin > 0.0) ? -(log2(fin) + (double)K) * LN2D : 0.0;
        loss_out[n] = (float)(loss / (double)(tl > 0 ? tl : 1));
    }
}

// ---------------- Pass 3: mean over batch ----------------
__global__ __launch_bounds__(64) void reduce_kernel(const float* __restrict__ loss,
                                                    float* __restrict__ out, int N) {
    float s = 0.0f;
    for (int i = threadIdx.x; i < N; i += 64) s += loss[i];
#pragma unroll
    for (int off = 32; off; off >>= 1) s += __shfl_xor(s, off, 64);
    if (threadIdx.x == 0) out[0] = s / (float)N;
}

extern "C" void kernel_launch(void* const* d_in, const int* in_sizes, int n_in,
                              void* d_out, int out_size, void* d_ws, size_t ws_size,
                              hipStream_t stream) {
    const float* preds = (const float*)d_in[0];
    const int* targets = (const int*)d_in[1];
    const int N = in_sizes[1] / 128;          // 128
    const int T = 1024;

    // ws layout: gath [N*131072] | blank [N*T] | loss [N]   (~64.6 MB)
    float* gath = (float*)d_ws;
    float* blank = gath + (size_t)N * 131072;
    float* loss = blank + (size_t)N * T;
    float* out = (float*)d_out;

    gather_kernel<<<N * 64, 256, 0, stream>>>(preds, targets, gath, blank);
    ctc_alpha_kernel<<<N, 64, 0, stream>>>(gath, blank, targets, loss);
    reduce_kernel<<<1, 64, 0, stream>>>(loss, out, N);
}

// Round 6
// 265.500 us; speedup vs baseline: 2.1813x; 1.0629x over previous
//
#include <hip/hip_runtime.h>

#define L2E 1.4426950408889634f
#define LN2D 0.6931471805599453

// ---- async global->LDS DMA (16B per lane: lds_base + lane*16) ----
__device__ __forceinline__ void async_copy16(const float* g, float* l) {
    __builtin_amdgcn_global_load_lds(
        (const __attribute__((address_space(1))) void*)g,
        (__attribute__((address_space(3))) void*)l, 16, 0, 0);
}
// gfx9 s_waitcnt imm: vmcnt[3:0]|expcnt[6:4]|lgkmcnt[11:8]|vmcnt_hi[15:14]
__device__ __forceinline__ void wait_vm28() { __builtin_amdgcn_s_waitcnt(0x4F7C); }  // vmcnt(28)
__device__ __forceinline__ void wait_vm0()  { __builtin_amdgcn_s_waitcnt(0x0F70); }  // vmcnt(0)

// f64 lane shifts via 2x 32-bit DPP; bound_ctrl=1 -> 0.0 fill. Pure VALU.
__device__ __forceinline__ double dpp_sr1_f64(double x) {  // lane l <- lane l-1 (lane0 -> 0)
    const int lo = __builtin_amdgcn_update_dpp(0, __double2loint(x), 0x138, 0xF, 0xF, true);
    const int hi = __builtin_amdgcn_update_dpp(0, __double2hiint(x), 0x138, 0xF, 0xF, true);
    return __hiloint2double(hi, lo);
}
__device__ __forceinline__ double dpp_sl1_f64(double x) {  // lane l <- lane l+1 (lane63 -> 0)
    const int lo = __builtin_amdgcn_update_dpp(0, __double2loint(x), 0x130, 0xF, 0xF, true);
    const int hi = __builtin_amdgcn_update_dpp(0, __double2hiint(x), 0x130, 0xF, 0xF, true);
    return __hiloint2double(hi, lo);
}
// wave-wide int max broadcast (off critical path; only positions the f64 window)
__device__ __forceinline__ int wave_imax(int v) {
    int t;
#define DM(ctrl) t = __builtin_amdgcn_update_dpp(v, v, (ctrl), 0xF, 0xF, false); v = (v > t) ? v : t
    DM(0x111); DM(0x112); DM(0x114); DM(0x118);
    DM(0x142); DM(0x143);
#undef DM
    return __builtin_amdgcn_readlane(v, 63);
}

// ---------------- Pass 1: fused softmax + label gather (probabilities) ----------------
// Chunk c = 4 timesteps. gath[n][c][ lane*4+k ] = p(4c+k, tg[2lane]);
//                        gath[n][c][256+lane*4+k] = p(4c+k, tg[2lane+1]); blank[n][t] = p(t, 0)
__global__ __launch_bounds__(256) void gather_kernel(const float* __restrict__ preds,
                                                     const int* __restrict__ targets,
                                                     float* __restrict__ gath,
                                                     float* __restrict__ blank) {
    constexpr int T = 1024, C = 256, L = 128;
    const int n = blockIdx.x >> 6;
    const int c = ((blockIdx.x & 63) << 2) + (threadIdx.x >> 6);
    const int lane = threadIdx.x & 63;
    const int w = threadIdx.x >> 6;

    const float* __restrict__ P = preds + ((size_t)n * T + (size_t)c * 4) * C;
    const int* __restrict__ tg = targets + (size_t)n * L;
    const int tgA = tg[2 * lane + 0];
    const int tgB = tg[2 * lane + 1];

    __shared__ float sRow[4][4][C];
    float m_k[4], r_k[4];
#pragma unroll
    for (int k = 0; k < 4; ++k) {
        const float4 v = reinterpret_cast<const float4*>(P + (size_t)k * C)[lane];
        reinterpret_cast<float4*>(&sRow[w][k][0])[lane] = v;
        float m = fmaxf(fmaxf(v.x, v.y), fmaxf(v.z, v.w));
#pragma unroll
        for (int off = 32; off; off >>= 1) m = fmaxf(m, __shfl_xor(m, off, 64));
        float s = exp2f((v.x - m) * L2E) + exp2f((v.y - m) * L2E) +
                  exp2f((v.z - m) * L2E) + exp2f((v.w - m) * L2E);
#pragma unroll
        for (int off = 32; off; off >>= 1) s += __shfl_xor(s, off, 64);
        m_k[k] = m; r_k[k] = 1.0f / s;
    }
    float4 gA, gB;
    gA.x = exp2f((sRow[w][0][tgA] - m_k[0]) * L2E) * r_k[0];
    gA.y = exp2f((sRow[w][1][tgA] - m_k[1]) * L2E) * r_k[1];
    gA.z = exp2f((sRow[w][2][tgA] - m_k[2]) * L2E) * r_k[2];
    gA.w = exp2f((sRow[w][3][tgA] - m_k[3]) * L2E) * r_k[3];
    gB.x = exp2f((sRow[w][0][tgB] - m_k[0]) * L2E) * r_k[0];
    gB.y = exp2f((sRow[w][1][tgB] - m_k[1]) * L2E) * r_k[1];
    gB.z = exp2f((sRow[w][2][tgB] - m_k[2]) * L2E) * r_k[2];
    gB.w = exp2f((sRow[w][3][tgB] - m_k[3]) * L2E) * r_k[3];

    float* gp = gath + ((size_t)n * 256 + c) * 512;
    *reinterpret_cast<float4*>(gp + 4 * lane) = gA;
    *reinterpret_cast<float4*>(gp + 256 + 4 * lane) = gB;
    if (lane == 0) {
        float4 b;
        b.x = exp2f((sRow[w][0][0] - m_k[0]) * L2E) * r_k[0];
        b.y = exp2f((sRow[w][1][0] - m_k[1]) * L2E) * r_k[1];
        b.z = exp2f((sRow[w][2][0] - m_k[2]) * L2E) * r_k[2];
        b.w = exp2f((sRow[w][3][0] - m_k[3]) * L2E) * r_k[3];
        *reinterpret_cast<float4*>(blank + (size_t)n * T + (size_t)c * 4) = b;
    }
}

// ---------------- Pass 2: forward-backward alpha/beta, f64 linear, one wave per n. ----------
// alpha runs t=0..511 (chunks 0..127), beta runs t=1023..511 (chunks 255..128), interleaved
// for ILP. P = sum_s alpha_511(s)*beta_511(s). Lane l: states 4l..4l+3 (+A4/B4 for state 256).
// alpha cross-lane: prev lane's A3 via wf_sr1. beta: products g0,g1 shift down via wf_sl1.
// LDS ring: slots 0..7 alpha, 8..15 beta; 4 DMA per pair, wait vmcnt(28), all in-bounds.
__global__ __launch_bounds__(64) void ctc_alpha_kernel(const float* __restrict__ gath,
                                                       const float* __restrict__ blank,
                                                       const int* __restrict__ targets,
                                                       float* __restrict__ loss_out) {
    constexpr int T = 1024, L = 128;
    __shared__ float sG[16 * 512];     // 32 KB ring
    __shared__ float sBlank[T];        // 4 KB

    const int n = blockIdx.x;
    const int lane = threadIdx.x;
    const int* __restrict__ tg = targets + (size_t)n * L;

    const int tA = tg[2 * lane + 0];
    const int tB = tg[2 * lane + 1];
    int tPrev = __shfl_up(tB, 1, 64);
    if (lane == 0) tPrev = 0;
    const int skipAi = (tA != 0 && tA != tPrev) ? 1 : 0;
    const bool skipA = skipAi != 0;
    const bool skipB = (tB != 0) && (tB != tA);
    const double mBd = skipB ? 1.0 : 0.0;
    const double mA1d = (double)__shfl_down(skipAi, 1, 64);  // skipA of lane l+1 (lane63: x0)

    int cnt = (tA != 0) + (tB != 0);
#pragma unroll
    for (int off = 32; off; off >>= 1) cnt += __shfl_xor(cnt, off, 64);
    const int tl = cnt;
    int i1 = 2 * tl;       if (i1 > 256) i1 = 256;
    int i0 = 2 * tl - 1;   if (i0 < 0) i0 += 257;  // JAX negative-index wrap

    const float* __restrict__ gn = gath + (size_t)n * 131072;
    const float* __restrict__ bn = blank + (size_t)n * T;

    wait_vm0();  // drain target loads so DMA issue-order accounting below is exact

    // preload: 4 blank + 8 pairs x (2 alpha + 2 beta) = 36 issues
#pragma unroll
    for (int i = 0; i < 4; ++i) async_copy16(bn + i * 256 + lane * 4, &sBlank[i * 256]);
#pragma unroll
    for (int i = 0; i < 8; ++i) {
        async_copy16(gn + i * 512 + lane * 4,       &sG[i * 512]);
        async_copy16(gn + i * 512 + 256 + lane * 4, &sG[i * 512 + 256]);
        const int q = 255 - i;
        async_copy16(gn + q * 512 + lane * 4,       &sG[(8 + i) * 512]);
        async_copy16(gn + q * 512 + 256 + lane * 4, &sG[(8 + i) * 512 + 256]);
    }

    // alpha state + scale; beta state + scale
    double A0, A1, A2, A3, A4;
    double B0, B1, B2, B3, B4;
    double scA = 1.0, scB = 1.0;
    int eA = 0, eB = 0, KA = 0, KB = 0;

    // beta init at t=1023: indicator of final states i1/i0
    {
        const int s0 = 4 * lane;
        B0 = (s0 == i1 || s0 == i0) ? 1.0 : 0.0;
        B1 = (s0 + 1 == i1 || s0 + 1 == i0) ? 1.0 : 0.0;
        B2 = (s0 + 2 == i1 || s0 + 2 == i0) ? 1.0 : 0.0;
        B3 = (s0 + 3 == i1 || s0 + 3 == i0) ? 1.0 : 0.0;
        B4 = (lane == 63 && (i1 == 256 || i0 == 256)) ? 1.0 : 0.0;
    }

#define ASTEP(PB, PA, PB2) do {                                                 \
        const double p3 = dpp_sr1_f64(A3);                                      \
        const double u0 = A0 + p3;                                              \
        const double u1 = A1 + A0 + (skipA ? p3 : 0.0);                         \
        const double u2 = A2 + A1;                                              \
        const double u3 = A3 + A2 + (skipB ? A1 : 0.0);                         \
        const double u4 = A4 + A3;                                              \
        A0 = u0 * (PB); A1 = u1 * (PA); A2 = u2 * (PB);                         \
        A3 = u3 * (PB2); A4 = u4 * (PB);                                        \
    } while (0)

    // beta_t(s) = sum_{s'=s..s+2} T(s,s') p(t+1,lab(s')) beta_{t+1}(s'); g_s = p*beta_s
#define BSTEP(PBF, PAF, PBF2) do {                                              \
        const double pb_ = (PBF);                                               \
        const double g0 = pb_ * B0;                                             \
        const double g1 = (PAF) * B1;                                           \
        const double g2 = pb_ * B2;                                             \
        const double g3 = (PBF2) * B3;                                          \
        const double g4 = pb_ * B4;                                             \
        double G4 = dpp_sl1_f64(g0);                                            \
        G4 = (lane == 63) ? g4 : G4;                                            \
        const double G5 = dpp_sl1_f64(g1);                                      \
        B0 = g0 + g1;                                                           \
        B1 = fma(mBd, g3, g1 + g2);                                             \
        B2 = g2 + g3;                                                           \
        B3 = fma(mA1d, G5, g3 + G4);                                            \
        B4 = g4;                                                                \
    } while (0)

    // One pair: alpha chunk p (t ascending) interleaved with beta chunk 255-p (t descending).
#define PAIRBODY(P_, FIRST_)  do {                                              \
        const int sl_ = (P_) & 7;                                               \
        wait_vm28();                                                            \
        const float4 aA = *reinterpret_cast<const float4*>(&sG[sl_ * 512 + 4 * lane]);        \
        const float4 aB = *reinterpret_cast<const float4*>(&sG[sl_ * 512 + 256 + 4 * lane]);  \
        const float4 ab = *reinterpret_cast<const float4*>(&sBlank[4 * (P_)]);                \
        const float4 bA = *reinterpret_cast<const float4*>(&sG[(8 + sl_) * 512 + 4 * lane]);       \
        const float4 bB = *reinterpret_cast<const float4*>(&sG[(8 + sl_) * 512 + 256 + 4 * lane]); \
        const float4 bb = *reinterpret_cast<const float4*>(&sBlank[4 * (255 - (P_))]);        \
        { const int cp = (P_) + 8, q = 247 - (P_);                              \
          async_copy16(gn + cp * 512 + lane * 4,       &sG[sl_ * 512]);         \
          async_copy16(gn + cp * 512 + 256 + lane * 4, &sG[sl_ * 512 + 256]);   \
          async_copy16(gn + q * 512 + lane * 4,        &sG[(8 + sl_) * 512]);   \
          async_copy16(gn + q * 512 + 256 + lane * 4,  &sG[(8 + sl_) * 512 + 256]); } \
        if (FIRST_) {                                                           \
            A0 = lane ? 0.0 : (double)ab.x;                                     \
            A1 = lane ? 0.0 : (double)aA.x;                                     \
            A2 = 0.0; A3 = 0.0; A4 = 0.0;                                       \
        } else {                                                                \
            ASTEP((double)ab.x, (double)aA.x, (double)aB.x);                    \
        }                                                                       \
        BSTEP((double)bb.w, (double)bA.w, (double)bB.w);                        \
        ASTEP((double)ab.y, (double)aA.y, (double)aB.y);                        \
        BSTEP((double)bb.z, (double)bA.z, (double)bB.z);                        \
        ASTEP((double)ab.z, (double)aA.z, (double)aB.z);                        \
        BSTEP((double)bb.y, (double)bA.y, (double)bB.y);                        \
        ASTEP((double)ab.w, (double)aA.w, (double)aB.w);                        \
        BSTEP((double)bb.x, (double)bA.x, (double)bB.x);                        \
    } while (0)

    // apply previously measured pow2 scale, then measure anew (latency hides over next 8 steps)
#define RESCALES() do {                                                         \
        A0 *= scA; A1 *= scA; A2 *= scA; A3 *= scA; A4 *= scA; KA += eA;        \
        B0 *= scB; B1 *= scB; B2 *= scB; B3 *= scB; B4 *= scB; KB += eB;        \
        const double ma = fmax(fmax(fmax(A0, A1), fmax(A2, A3)), A4);           \
        const double mb = fmax(fmax(fmax(B0, B1), fmax(B2, B3)), B4);           \
        int ea_ = ((__double2hiint(ma) >> 20) & 0x7FF) - 1023;                  \
        int eb_ = ((__double2hiint(mb) >> 20) & 0x7FF) - 1023;                  \
        ea_ = wave_imax(ea_); eb_ = wave_imax(eb_);                             \
        ea_ = ea_ < -960 ? -960 : (ea_ > 960 ? 960 : ea_);                      \
        eb_ = eb_ < -960 ? -960 : (eb_ > 960 ? 960 : eb_);                      \
        eA = ea_; scA = __hiloint2double((1023 - ea_) << 20, 0);                \
        eB = eb_; scB = __hiloint2double((1023 - eb_) << 20, 0);                \
    } while (0)

    PAIRBODY(0, true);
    for (int p = 1; p < 127; p += 2) {
        PAIRBODY(p, false);
        RESCALES();
        PAIRBODY(p + 1, false);
    }
    PAIRBODY(127, false);
    RESCALES();
    // apply last pending scale
    A0 *= scA; A1 *= scA; A2 *= scA; A3 *= scA; A4 *= scA; KA += eA;
    B0 *= scB; B1 *= scB; B2 *= scB; B3 *= scB; B4 *= scB; KB += eB;
#undef RESCALES
#undef PAIRBODY
#undef BSTEP
#undef ASTEP

    // P = sum_s alpha_511(s) * beta_511(s); A4 is a replica except lane 63 (state 256)
    double S = A0 * B0 + A1 * B1 + A2 * B2 + A3 * B3;
    S += (lane == 63) ? A4 * B4 : 0.0;
#pragma unroll
    for (int off = 32; off; off >>= 1) S += __shfl_xor(S, off, 64);
    if (lane == 0) {
        const double loss = (S > 0.0) ? -(log2(S) + (double)(KA + KB)) * LN2D : 0.0;
        loss_out[n] = (float)(loss / (double)(tl > 0 ? tl : 1));
    }
}

// ---------------- Pass 3: mean over batch ----------------
__global__ __launch_bounds__(64) void reduce_kernel(const float* __restrict__ loss,
                                                    float* __restrict__ out, int N) {
    float s = 0.0f;
    for (int i = threadIdx.x; i < N; i += 64) s += loss[i];
#pragma unroll
    for (int off = 32; off; off >>= 1) s += __shfl_xor(s, off, 64);
    if (threadIdx.x == 0) out[0] = s / (float)N;
}

extern "C" void kernel_launch(void* const* d_in, const int* in_sizes, int n_in,
                              void* d_out, int out_size, void* d_ws, size_t ws_size,
                              hipStream_t stream) {
    const float* preds = (const float*)d_in[0];
    const int* targets = (const int*)d_in[1];
    const int N = in_sizes[1] / 128;          // 128
    const int T = 1024;

    // ws layout: gath [N*131072] | blank [N*T] | loss [N]   (~64.6 MB)
    float* gath = (float*)d_ws;
    float* blank = gath + (size_t)N * 131072;
    float* loss = blank + (size_t)N * T;
    float* out = (float*)d_out;

    gather_kernel<<<N * 64, 256, 0, stream>>>(preds, targets, gath, blank);
    ctc_alpha_kernel<<<N, 64, 0, stream>>>(gath, blank, targets, loss);
    reduce_kernel<<<1, 64, 0, stream>>>(loss, out, N);
}